// Round 1
// baseline (14715.903 us; speedup 1.0000x reference)
//
#include <hip/hip_runtime.h>
#include <hip/hip_cooperative_groups.h>
#include <math.h>

namespace cg = cooperative_groups;

#define NB 256
#define NT 1024
#define NW 16      // waves per block
#define TT 100
#define MM 10
#define NN 10
#define HID 2000
#define H1 1600
#define H2 400
#define G3 6000    // 3*HID

__device__ __forceinline__ float sigf(float x) { return 1.f / (1.f + __expf(-x)); }
__device__ __forceinline__ float tanhfast(float x) { return 2.f / (1.f + __expf(-2.f * x)) - 1.f; }

// one row dot-product per wave; x in LDS; K % 4 == 0
__device__ __forceinline__ float rowdot(const float* __restrict__ row,
                                        const float* __restrict__ x, int K, int ln) {
  float acc = 0.f;
  for (int k = ln * 4; k + 3 < K; k += 256) {
    const float4 w  = *reinterpret_cast<const float4*>(row + k);
    const float4 xv = *reinterpret_cast<const float4*>(x + k);
    acc = fmaf(w.x, xv.x, acc);
    acc = fmaf(w.y, xv.y, acc);
    acc = fmaf(w.z, xv.z, acc);
    acc = fmaf(w.w, xv.w, acc);
  }
  #pragma unroll
  for (int off = 32; off; off >>= 1) acc += __shfl_xor(acc, off, 64);
  return acc;
}

__global__ __launch_bounds__(NT)
void knet_kernel(const float* __restrict__ y, const float* __restrict__ m1x0,
                 const float* __restrict__ F, const float* __restrict__ Hm,
                 const float* __restrict__ h0,
                 const float* __restrict__ W1, const float* __restrict__ b1,
                 const float* __restrict__ Wi0, const float* __restrict__ Wh0,
                 const float* __restrict__ bi0, const float* __restrict__ bh0,
                 const float* __restrict__ Wi1, const float* __restrict__ Wh1,
                 const float* __restrict__ bi1, const float* __restrict__ bh1,
                 const float* __restrict__ W2, const float* __restrict__ b2,
                 const float* __restrict__ W3, const float* __restrict__ b3,
                 float* __restrict__ out, float* __restrict__ ws)
{
  cg::grid_group grid = cg::this_grid();
  const int blk = blockIdx.x, tid = threadIdx.x;
  const int wv = tid >> 6, ln = tid & 63;

  float* a_ws   = ws;            // 1600
  float* gi0_ws = ws + 1600;     // 6000
  float* gh0_ws = ws + 7600;     // 6000
  float* gi1_ws = ws + 13600;    // 6000
  float* gh1_ws = ws + 19600;    // 6000
  float* g_ws   = ws + 25600;    // 400
  float* h1b    = ws + 26000;    // 2*2000 ping-pong
  float* h2b    = ws + 30000;    // 2*2000 ping-pong

  __shared__ __align__(16) float xs[2048];
  __shared__ float post_s[MM], prevpost_s[MM], prevprior_s[MM], prior_s[MM];
  __shared__ float dy_s[NN], yprev_s[NN], tmp_s[MM];
  __shared__ float d1_s[NN], d3_s[MM], d4_s[MM];
  __shared__ float kin_s[32], nrm_s[3];
  __shared__ float v_s[MM * NN], np_s[MM];

  for (int t = 0; t < TT; ++t) {
    // ---------------- Phase AE ----------------
    if (blk == NB - 1) {
      if (t > 0) {
        // finalize step t-1: v = W3@g + b3, new_post = prior + KG@dy
        for (int j = tid; j < H2; j += NT) xs[j] = g_ws[j];
        __syncthreads();
        for (int r = wv; r < MM * NN; r += NW) {
          float acc = rowdot(W3 + (size_t)r * H2, xs, H2, ln);
          if (ln == 0) v_s[r] = acc + b3[r];
        }
        __syncthreads();
        if (tid < MM) {
          float np = prior_s[tid];
          #pragma unroll
          for (int j = 0; j < NN; ++j) np = fmaf(v_s[tid * NN + j], dy_s[j], np);
          out[tid * TT + (t - 1)] = np;
          np_s[tid] = np;
        }
        __syncthreads();
        if (tid < MM) {
          prevpost_s[tid]  = post_s[tid];
          prevprior_s[tid] = prior_s[tid];
          post_s[tid]      = np_s[tid];
        }
        __syncthreads();
      } else {
        // init carry in LDS
        if (tid < MM) {
          post_s[tid]      = m1x0[tid];
          prevpost_s[tid]  = 0.f;
          prevprior_s[tid] = m1x0[tid];
          float tv = 0.f;
          for (int j = 0; j < MM; ++j) tv = fmaf(F[tid * MM + j], m1x0[j], tv);
          tmp_s[tid] = tv;
        }
        __syncthreads();
        if (tid < NN) {
          float yp = 0.f;
          for (int j = 0; j < MM; ++j) yp = fmaf(Hm[tid * MM + j], tmp_s[j], yp);
          yprev_s[tid] = yp;
        }
        __syncthreads();
      }
      // features for step t
      if (tid < MM) {
        float pr = 0.f;
        for (int j = 0; j < MM; ++j) pr = fmaf(F[tid * MM + j], post_s[j], pr);
        prior_s[tid] = pr;
      }
      __syncthreads();
      if (tid < NN) {
        float my = 0.f;
        for (int j = 0; j < MM; ++j) my = fmaf(Hm[tid * MM + j], prior_s[j], my);
        float yt = y[tid * TT + t];
        dy_s[tid] = yt - my;
        d1_s[tid] = yt - ((t == 0) ? yprev_s[tid] : y[tid * TT + (t - 1)]);
        d3_s[tid] = post_s[tid] - prevpost_s[tid];
        d4_s[tid] = post_s[tid] - prevprior_s[tid];
      }
      __syncthreads();
      if (tid == 0) {
        float n1 = 0.f, n3 = 0.f, n4 = 0.f;
        for (int j = 0; j < NN; ++j) n1 += d1_s[j] * d1_s[j];
        for (int j = 0; j < MM; ++j) { n3 += d3_s[j] * d3_s[j]; n4 += d4_s[j] * d4_s[j]; }
        nrm_s[0] = fmaxf(sqrtf(n1), 1e-12f);
        nrm_s[1] = fmaxf(sqrtf(n3), 1e-12f);
        nrm_s[2] = fmaxf(sqrtf(n4), 1e-12f);
      }
      __syncthreads();
      if (tid < NN) kin_s[tid] = d1_s[tid] / nrm_s[0];
      if (tid < MM) {
        kin_s[NN + tid]      = d3_s[tid] / nrm_s[1];
        kin_s[NN + MM + tid] = d4_s[tid] / nrm_s[2];
      }
      __syncthreads();
      // a = relu(W1 @ kin + b1): thread-per-row, K=30
      for (int r = tid; r < H1; r += NT) {
        float acc = b1[r];
        const float* row = W1 + (size_t)r * 30;
        #pragma unroll
        for (int k = 0; k < 30; ++k) acc = fmaf(row[k], kin_s[k], acc);
        a_ws[r] = fmaxf(acc, 0.f);
      }
    } else {
      // gh0 = Wh0@h1 + bh0  (blocks 0..126) ; gh1 = Wh1@h2 + bh1 (blocks 127..254)
      const float* h1cur = (t == 0) ? h0 : (h1b + ((t - 1) & 1) * HID);
      const float* h2cur = (t == 0) ? (h0 + HID) : (h2b + ((t - 1) & 1) * HID);
      const bool grp0 = (blk < 127);
      const float* xsrc = grp0 ? h1cur : h2cur;
      for (int j = tid; j < HID; j += NT) xs[j] = xsrc[j];
      __syncthreads();
      if (grp0) {
        const int gw = blk * NW + wv;              // 0..2031
        for (int r = gw; r < G3; r += 127 * NW) {
          float acc = rowdot(Wh0 + (size_t)r * HID, xs, HID, ln);
          if (ln == 0) gh0_ws[r] = acc + bh0[r];
        }
      } else {
        const int gw = (blk - 127) * NW + wv;      // 0..2047
        for (int r = gw; r < G3; r += 128 * NW) {
          float acc = rowdot(Wh1 + (size_t)r * HID, xs, HID, ln);
          if (ln == 0) gh1_ws[r] = acc + bh1[r];
        }
      }
    }
    grid.sync();

    // ---------------- Phase B: gi0 = Wi0@a + bi0 ----------------
    for (int j = tid; j < H1; j += NT) xs[j] = a_ws[j];
    __syncthreads();
    {
      const int gw = blk * NW + wv;                // 0..4095
      for (int r = gw; r < G3; r += NB * NW) {
        float acc = rowdot(Wi0 + (size_t)r * H1, xs, H1, ln);
        if (ln == 0) gi0_ws[r] = acc + bi0[r];
      }
    }
    grid.sync();

    // ---------------- Phase C: h1n (redundant) then gi1 = Wi1@h1n + bi1 ----------------
    {
      const float* h1cur = (t == 0) ? h0 : (h1b + ((t - 1) & 1) * HID);
      for (int j = tid; j < HID; j += NT) {
        float r = sigf(gi0_ws[j] + gh0_ws[j]);
        float z = sigf(gi0_ws[HID + j] + gh0_ws[HID + j]);
        float n = tanhfast(gi0_ws[2 * HID + j] + r * gh0_ws[2 * HID + j]);
        xs[j] = (1.f - z) * n + z * h1cur[j];
      }
      __syncthreads();
      if (blk == 0) {
        float* h1nxt = h1b + (t & 1) * HID;
        for (int j = tid; j < HID; j += NT) h1nxt[j] = xs[j];
      }
      const int gw = blk * NW + wv;
      for (int r = gw; r < G3; r += NB * NW) {
        float acc = rowdot(Wi1 + (size_t)r * HID, xs, HID, ln);
        if (ln == 0) gi1_ws[r] = acc + bi1[r];
      }
    }
    grid.sync();

    // ---------------- Phase D: h2n (redundant) then g = relu(W2@h2n + b2) ----------------
    {
      const float* h2cur = (t == 0) ? (h0 + HID) : (h2b + ((t - 1) & 1) * HID);
      if (blk <= 25) {
        for (int j = tid; j < HID; j += NT) {
          float r = sigf(gi1_ws[j] + gh1_ws[j]);
          float z = sigf(gi1_ws[HID + j] + gh1_ws[HID + j]);
          float n = tanhfast(gi1_ws[2 * HID + j] + r * gh1_ws[2 * HID + j]);
          xs[j] = (1.f - z) * n + z * h2cur[j];
        }
      }
      __syncthreads();
      if (blk < 25) {
        const int r = blk * NW + wv;               // 0..399 (one row per wave)
        float acc = rowdot(W2 + (size_t)r * HID, xs, HID, ln);
        if (ln == 0) g_ws[r] = fmaxf(acc + b2[r], 0.f);
      } else if (blk == 25) {
        float* h2nxt = h2b + (t & 1) * HID;
        for (int j = tid; j < HID; j += NT) h2nxt[j] = xs[j];
      }
    }
    grid.sync();
  }

  // ---------------- Tail: finalize step T-1 ----------------
  if (blk == NB - 1) {
    for (int j = tid; j < H2; j += NT) xs[j] = g_ws[j];
    __syncthreads();
    for (int r = wv; r < MM * NN; r += NW) {
      float acc = rowdot(W3 + (size_t)r * H2, xs, H2, ln);
      if (ln == 0) v_s[r] = acc + b3[r];
    }
    __syncthreads();
    if (tid < MM) {
      float np = prior_s[tid];
      #pragma unroll
      for (int j = 0; j < NN; ++j) np = fmaf(v_s[tid * NN + j], dy_s[j], np);
      out[tid * TT + (TT - 1)] = np;
    }
  }
}

extern "C" void kernel_launch(void* const* d_in, const int* in_sizes, int n_in,
                              void* d_out, int out_size, void* d_ws, size_t ws_size,
                              hipStream_t stream) {
  const float* y    = (const float*)d_in[0];
  const float* m1x0 = (const float*)d_in[1];
  const float* F    = (const float*)d_in[2];
  const float* Hm   = (const float*)d_in[3];
  const float* h0   = (const float*)d_in[4];
  const float* W1   = (const float*)d_in[5];
  const float* b1   = (const float*)d_in[6];
  const float* Wi0  = (const float*)d_in[7];
  const float* Wh0  = (const float*)d_in[8];
  const float* bi0  = (const float*)d_in[9];
  const float* bh0  = (const float*)d_in[10];
  const float* Wi1  = (const float*)d_in[11];
  const float* Wh1  = (const float*)d_in[12];
  const float* bi1  = (const float*)d_in[13];
  const float* bh1  = (const float*)d_in[14];
  const float* W2   = (const float*)d_in[15];
  const float* b2   = (const float*)d_in[16];
  const float* W3   = (const float*)d_in[17];
  const float* b3   = (const float*)d_in[18];
  float* out = (float*)d_out;
  float* ws  = (float*)d_ws;

  void* args[] = { &y, &m1x0, &F, &Hm, &h0, &W1, &b1, &Wi0, &Wh0, &bi0, &bh0,
                   &Wi1, &Wh1, &bi1, &bh1, &W2, &b2, &W3, &b3, &out, &ws };
  hipLaunchCooperativeKernel((const void*)knet_kernel, dim3(NB), dim3(NT),
                             args, 0, stream);
}